// Round 1
// baseline (132.969 us; speedup 1.0000x reference)
//
#include <hip/hip_runtime.h>

typedef __attribute__((ext_vector_type(4))) float f32x4;
typedef __bf16 bf16x8 __attribute__((ext_vector_type(8)));

#define T_TOK 8192   // B*S
#define DIM   1024   // D
#define NRCOL 2048   // N_FEAT * R

static __device__ __forceinline__ unsigned short f2bf(float f) {
  unsigned int u = __builtin_bit_cast(unsigned int, f);
  u += 0x7fffu + ((u >> 16) & 1u);          // RNE
  return (unsigned short)(u >> 16);
}
static __device__ __forceinline__ float bfbits2f(unsigned int lo16) {
  return __builtin_bit_cast(float, lo16 << 16);
}
static __device__ __forceinline__ void gload16(const void* g, void* l) {
  __builtin_amdgcn_global_load_lds((const __attribute__((address_space(1))) void*)g,
                                   (__attribute__((address_space(3))) void*)l, 16, 0, 0);
}

// ---------------- f32 -> bf16 straight cast (x) ----------------
__global__ __launch_bounds__(256) void cvt_f32_bf16(const float* __restrict__ in,
                                                    unsigned short* __restrict__ out,
                                                    int n4) {
  int i = blockIdx.x * 256 + threadIdx.x;
  const int stride = gridDim.x * 256;
  const float4* in4 = (const float4*)in;
  uint2* o4 = (uint2*)out;
  for (; i < n4; i += stride) {
    float4 v = in4[i];
    uint2 o;
    o.x = (unsigned)f2bf(v.x) | ((unsigned)f2bf(v.y) << 16);
    o.y = (unsigned)f2bf(v.z) | ((unsigned)f2bf(v.w) << 16);
    o4[i] = o;
  }
}

// ---------------- tiled transpose + cast: dst[c*rows + r] = src[r*cols + c] ----------------
__global__ __launch_bounds__(256) void tcvt(const float* __restrict__ src,
                                            unsigned short* __restrict__ dst,
                                            int rows, int cols,
                                            long sstride, long dstride) {
  src += (size_t)blockIdx.z * sstride;
  dst += (size_t)blockIdx.z * dstride;
  __shared__ float tile[32][33];
  const int tx = threadIdx.x & 31, ty = threadIdx.x >> 5;
  const int r0 = blockIdx.y * 32, c0 = blockIdx.x * 32;
  #pragma unroll
  for (int i = 0; i < 32; i += 8)
    tile[ty + i][tx] = src[(size_t)(r0 + ty + i) * cols + c0 + tx];
  __syncthreads();
  #pragma unroll
  for (int i = 0; i < 32; i += 8)
    dst[(size_t)(c0 + ty + i) * rows + r0 + tx] = f2bf(tile[tx][ty + i]);
}

// ---------------- bf16 GEMM: C[M,N] = A[M,K] * Bt[N,K]^T ----------------
// 128x128 tile, BK=64, 256 threads (4 waves 2x2, each 64x64), 16x16x32 MFMA.
// LDS staged via global_load_lds(16B) with chunk-XOR swizzle (both-sides involution).
template<bool OUT_BF16>
__global__ __launch_bounds__(256) void gemm_bt(const unsigned short* __restrict__ A,
                                               const unsigned short* __restrict__ Bt,
                                               void* __restrict__ Cp,
                                               int M, int N, int K) {
  __shared__ unsigned short As[128 * 64];
  __shared__ unsigned short Bs[128 * 64];
  const int tid = threadIdx.x;
  const int bx = blockIdx.x, by = blockIdx.y;
  const int lane = tid & 63;
  const int wv = tid >> 6;
  const int wm = wv >> 1, wn = wv & 1;
  const int lrow = lane & 15;
  const int lk = lane >> 4;

  const unsigned short* Ab = A + (size_t)by * 128 * K;
  const unsigned short* Bb = Bt + (size_t)bx * 128 * K;

  f32x4 acc[4][4];
  #pragma unroll
  for (int m = 0; m < 4; ++m)
    #pragma unroll
    for (int n = 0; n < 4; ++n)
      acc[m][n] = (f32x4){0.f, 0.f, 0.f, 0.f};

  const int nk = K >> 6;
  for (int kt = 0; kt < nk; ++kt) {
    // stage 16KB A-tile + 16KB B-tile; linear LDS dest, inverse-swizzled global src
    #pragma unroll
    for (int c = 0; c < 4; ++c) {
      const int L = c * 4096 + tid * 16;          // byte offset in tile
      const int row = L >> 7;                     // 128 B per row (BK=64 bf16)
      const int sc = ((L >> 4) & 7) ^ (row & 7);  // source 16B-chunk
      gload16(Ab + (size_t)row * K + kt * 64 + sc * 8, (void*)&As[L >> 1]);
      gload16(Bb + (size_t)row * K + kt * 64 + sc * 8, (void*)&Bs[L >> 1]);
    }
    __syncthreads();
    #pragma unroll
    for (int kk = 0; kk < 2; ++kk) {
      bf16x8 av[4], bv[4];
      #pragma unroll
      for (int m = 0; m < 4; ++m) {
        const int r = wm * 64 + m * 16 + lrow;
        const int ch = (kk * 4 + lk) ^ (r & 7);   // swizzled read
        av[m] = *(const bf16x8*)&As[r * 64 + ch * 8];
      }
      #pragma unroll
      for (int n = 0; n < 4; ++n) {
        const int r = wn * 64 + n * 16 + lrow;
        const int ch = (kk * 4 + lk) ^ (r & 7);
        bv[n] = *(const bf16x8*)&Bs[r * 64 + ch * 8];
      }
      #pragma unroll
      for (int m = 0; m < 4; ++m)
        #pragma unroll
        for (int n = 0; n < 4; ++n)
          acc[m][n] = __builtin_amdgcn_mfma_f32_16x16x32_bf16(av[m], bv[n], acc[m][n], 0, 0, 0);
    }
    __syncthreads();
  }

  // epilogue: C/D layout col=lane&15, row=(lane>>4)*4+reg
  #pragma unroll
  for (int m = 0; m < 4; ++m) {
    const int row0 = by * 128 + wm * 64 + m * 16 + lk * 4;
    #pragma unroll
    for (int n = 0; n < 4; ++n) {
      const int col = bx * 128 + wn * 64 + n * 16 + lrow;
      #pragma unroll
      for (int j = 0; j < 4; ++j) {
        const size_t idx = (size_t)(row0 + j) * N + col;
        if (OUT_BF16) ((unsigned short*)Cp)[idx] = f2bf(acc[m][n][j]);
        else          ((float*)Cp)[idx] = acc[m][n][j];
      }
    }
  }
}

// ---------------- middle: h_all, router softmax, M = sum_p w (x) h ----------------
// 4 waves/block, one token per wave; lane owns r = {2l, 2l+1}
__global__ __launch_bounds__(256) void middle_kernel(const unsigned short* __restrict__ AH,
                                                     const float* __restrict__ fp,
                                                     const float* __restrict__ femb,
                                                     const float* __restrict__ Wr,
                                                     unsigned short* __restrict__ Mout,
                                                     float* __restrict__ auxout) {
  __shared__ float G[16][16];       // G[n][j] = sum_ds femb[n][ds]*Wr[ds][j]
  __shared__ float hs[4][2][128];
  __shared__ float wsm[4][2][16];
  const int tid = threadIdx.x;
  {
    const int n = tid >> 4, j = tid & 15;
    float s = 0.f;
    #pragma unroll
    for (int ds = 0; ds < 64; ++ds) s += femb[n * 64 + ds] * Wr[ds * 16 + j];
    G[n][j] = s;
  }
  const int wv = tid >> 6, l = tid & 63;
  const int t = blockIdx.x * 4 + wv;

  float p0[16], p1[16];
  #pragma unroll
  for (int n = 0; n < 16; ++n) {
    p0[n] = fp[t * 16 + n];
    p1[n] = fp[T_TOK * 16 + t * 16 + n];
  }

  float h00 = 0.f, h01 = 0.f, h10 = 0.f, h11 = 0.f;
  const unsigned short* ahrow = AH + (size_t)t * NRCOL;
  #pragma unroll
  for (int n = 0; n < 16; ++n) {
    const unsigned int v = *(const unsigned int*)(ahrow + n * 128 + 2 * l);
    const float a0 = bfbits2f(v & 0xffffu);
    const float a1 = bfbits2f(v >> 16);
    h00 += a0 * p0[n]; h01 += a1 * p0[n];
    h10 += a0 * p1[n]; h11 += a1 * p1[n];
  }
  hs[wv][0][2 * l] = h00; hs[wv][0][2 * l + 1] = h01;
  hs[wv][1][2 * l] = h10; hs[wv][1][2 * l + 1] = h11;
  __syncthreads();

  if (l < 32) {
    const int p = l >> 4, j = l & 15;
    float s = 0.f;
    #pragma unroll
    for (int n = 0; n < 16; ++n) s += (p ? p1[n] : p0[n]) * G[n][j];
    for (int r = 0; r < 128; ++r) s += hs[wv][p][r] * Wr[(64 + r) * 16 + j];
    float mx = s;
    #pragma unroll
    for (int d = 1; d < 16; d <<= 1) mx = fmaxf(mx, __shfl_xor(mx, d, 64));
    const float e = __expf(s - mx);
    float sum = e;
    #pragma unroll
    for (int d = 1; d < 16; d <<= 1) sum += __shfl_xor(sum, d, 64);
    wsm[wv][p][j] = e / sum;
  }
  __syncthreads();

  unsigned short* mrow = Mout + (size_t)t * NRCOL;
  #pragma unroll
  for (int n = 0; n < 16; ++n) {
    const float w0 = wsm[wv][0][n], w1 = wsm[wv][1][n];
    const float m0 = w0 * h00 + w1 * h10;   // r = 2l
    const float m1 = w0 * h01 + w1 * h11;   // r = 2l+1
    const unsigned int pk = (unsigned)f2bf(m0) | ((unsigned)f2bf(m1) << 16);
    *(unsigned int*)(mrow + n * 128 + 2 * l) = pk;
  }
  if (blockIdx.x == 0 && tid == 0) auxout[0] = 0.f;
}

extern "C" void kernel_launch(void* const* d_in, const int* in_sizes, int n_in,
                              void* d_out, int out_size, void* d_ws, size_t ws_size,
                              hipStream_t stream) {
  const float* x    = (const float*)d_in[0];
  const float* fp   = (const float*)d_in[1];
  const float* fk   = (const float*)d_in[2];
  const float* rk   = (const float*)d_in[3];
  const float* femb = (const float*)d_in[4];
  const float* Wr   = (const float*)d_in[5];
  float* out = (float*)d_out;

  char* ws = (char*)d_ws;
  // lifetime-overlapped layout (68 MB):
  //  [0,16M)  Xbf   (dead after gemm1)   }  Mb [0,32M) written by middle
  //  [16,20M) W1t   (dead after gemm1)   }
  //  [32,36M) W2t
  //  [36,68M) AH
  unsigned short* Xbf = (unsigned short*)ws;
  unsigned short* W1t = (unsigned short*)(ws + 16u * 1024 * 1024);
  unsigned short* Mb  = (unsigned short*)ws;
  unsigned short* W2t = (unsigned short*)(ws + 32u * 1024 * 1024);
  unsigned short* AH  = (unsigned short*)(ws + 36u * 1024 * 1024);

  // x [8192,1024] f32 -> bf16
  cvt_f32_bf16<<<2048, 256, 0, stream>>>(x, Xbf, (T_TOK * DIM) / 4);
  // f_know [16][1024][128] -> W1t[(n*128+r)][1024] (per-n transpose)
  tcvt<<<dim3(128 / 32, 1024 / 32, 16), 256, 0, stream>>>(fk, W1t, 1024, 128,
                                                          1024L * 128, 128L * 1024);
  // r_know [2048][1024] -> W2t[1024][2048]
  tcvt<<<dim3(1024 / 32, 2048 / 32, 1), 256, 0, stream>>>(rk, W2t, 2048, 1024, 0, 0);
  // all_h = Xbf @ W1t^T  -> AH bf16 [8192][2048]
  gemm_bt<true><<<dim3(NRCOL / 128, T_TOK / 128), 256, 0, stream>>>(Xbf, W1t, AH,
                                                                    T_TOK, NRCOL, DIM);
  // routing + M
  middle_kernel<<<T_TOK / 4, 256, 0, stream>>>(AH, fp, femb, Wr, Mb, out + 8388608);
  // output = Mb @ W2t^T -> f32 d_out [8192][1024]
  gemm_bt<false><<<dim3(DIM / 128, T_TOK / 128), 256, 0, stream>>>(Mb, W2t, out,
                                                                   T_TOK, DIM, NRCOL);
}

// Round 2
// 119.956 us; speedup vs baseline: 1.1085x; 1.1085x over previous
//
#include <hip/hip_runtime.h>

typedef __attribute__((ext_vector_type(4))) float f32x4;
typedef __bf16 bf16x8 __attribute__((ext_vector_type(8)));
typedef unsigned short ushort_t;

#define T_TOK 8192   // B*S
#define DIM   1024   // D
#define NRCOL 2048   // N_FEAT * R

#define LGKM0() asm volatile("s_waitcnt lgkmcnt(0)" ::: "memory")
#define VMW(n)  asm volatile("s_waitcnt vmcnt(" #n ")" ::: "memory")
#define SB0()   __builtin_amdgcn_sched_barrier(0)
#define BAR()   __builtin_amdgcn_s_barrier()

static __device__ __forceinline__ unsigned short f2bf(float f) {
  unsigned int u = __builtin_bit_cast(unsigned int, f);
  u += 0x7fffu + ((u >> 16) & 1u);          // RNE
  return (unsigned short)(u >> 16);
}
static __device__ __forceinline__ float bfbits2f(unsigned int lo16) {
  return __builtin_bit_cast(float, lo16 << 16);
}
static __device__ __forceinline__ void gload16(const void* g, void* l) {
  __builtin_amdgcn_global_load_lds((const __attribute__((address_space(1))) void*)g,
                                   (__attribute__((address_space(3))) void*)l, 16, 0, 0);
}

// ---------------- f32 -> bf16 straight cast (x) ----------------
__global__ __launch_bounds__(256) void cvt_f32_bf16(const float* __restrict__ in,
                                                    unsigned short* __restrict__ out,
                                                    int n4) {
  int i = blockIdx.x * 256 + threadIdx.x;
  const int stride = gridDim.x * 256;
  const float4* in4 = (const float4*)in;
  uint2* o4 = (uint2*)out;
  for (; i < n4; i += stride) {
    float4 v = in4[i];
    uint2 o;
    o.x = (unsigned)f2bf(v.x) | ((unsigned)f2bf(v.y) << 16);
    o.y = (unsigned)f2bf(v.z) | ((unsigned)f2bf(v.w) << 16);
    o4[i] = o;
  }
}

// ---------------- tiled transpose + cast ----------------
__global__ __launch_bounds__(256) void tcvt(const float* __restrict__ src,
                                            unsigned short* __restrict__ dst,
                                            int rows, int cols,
                                            long sstride, long dstride) {
  src += (size_t)blockIdx.z * sstride;
  dst += (size_t)blockIdx.z * dstride;
  __shared__ float tile[32][33];
  const int tx = threadIdx.x & 31, ty = threadIdx.x >> 5;
  const int r0 = blockIdx.y * 32, c0 = blockIdx.x * 32;
  #pragma unroll
  for (int i = 0; i < 32; i += 8)
    tile[ty + i][tx] = src[(size_t)(r0 + ty + i) * cols + c0 + tx];
  __syncthreads();
  #pragma unroll
  for (int i = 0; i < 32; i += 8)
    dst[(size_t)(c0 + ty + i) * rows + r0 + tx] = f2bf(tile[tx][ty + i]);
}

// ---------------- bf16 GEMM: C[M,N] = A[M,K] * Bt[N,K]^T ----------------
// 256xBN tile, BK=64, 512 threads = 8 waves (2M x 4N), double-buffered LDS,
// counted-vmcnt pipeline (stage t+2 while computing t), XOR chunk swizzle,
// XCD-aware block swizzle. One barrier-pair per K-tile.
template<int BN, bool OUT_BF16>
__global__ __launch_bounds__(512) void gemm8(const ushort_t* __restrict__ A,
                                             const ushort_t* __restrict__ Bt,
                                             void* __restrict__ Cp,
                                             int N, int K) {
  constexpr int NF = BN / 64;       // n-frags per wave (4 N-waves)
  constexpr int BR = BN / 64;       // B staging rounds (8KB each)
  constexpr int LPT = 4 + BR;       // gload_lds instrs per thread per tile
  __shared__ ushort_t As[2][256 * 64];
  __shared__ ushort_t Bs[2][BN * 64];

  const int tid = threadIdx.x;
  // T1: bijective XCD swizzle (nwg = 256, divisible by 8)
  const int nx = gridDim.x;
  const int orig = blockIdx.y * nx + blockIdx.x;
  const int q = (nx * gridDim.y) >> 3;
  const int swz = (orig & 7) * q + (orig >> 3);
  const int bx = swz % nx, by = swz / nx;

  const int lane = tid & 63, wv = tid >> 6;
  const int wm = wv >> 2, wn = wv & 3;
  const int lrow = lane & 15, lk = lane >> 4;

  const ushort_t* Ab = A + (size_t)by * 256 * K;
  const ushort_t* Bb = Bt + (size_t)bx * BN * K;

  auto stage = [&](int c, int kt) {
    #pragma unroll
    for (int r = 0; r < 4; ++r) {
      const int off = r * 8192 + tid * 16;
      const int row = off >> 7;
      const int ch = ((off >> 4) & 7) ^ (row & 7);
      gload16(Ab + (size_t)row * K + kt * 64 + ch * 8, (void*)&As[c][off >> 1]);
    }
    #pragma unroll
    for (int r = 0; r < BR; ++r) {
      const int off = r * 8192 + tid * 16;
      const int row = off >> 7;
      const int ch = ((off >> 4) & 7) ^ (row & 7);
      gload16(Bb + (size_t)row * K + kt * 64 + ch * 8, (void*)&Bs[c][off >> 1]);
    }
  };

  f32x4 acc[8][NF];
  #pragma unroll
  for (int m = 0; m < 8; ++m)
    #pragma unroll
    for (int n = 0; n < NF; ++n)
      acc[m][n] = (f32x4){0.f, 0.f, 0.f, 0.f};

  const int nt = K >> 6;
  // prologue: stage tiles 0,1; wait tile0 landed (tile1 stays in flight)
  stage(0, 0);
  stage(1, 1);
  if constexpr (LPT == 8) VMW(8); else VMW(6);
  SB0(); BAR(); SB0();

  for (int t = 0; t < nt; ++t) {
    const int c = t & 1;
    // ds_read ALL fragments of buf[c] (swizzled)
    bf16x8 av[8][2], bv[NF][2];
    #pragma unroll
    for (int m = 0; m < 8; ++m)
      #pragma unroll
      for (int ks = 0; ks < 2; ++ks) {
        const int row = wm * 128 + m * 16 + lrow;
        const int ch = (ks * 4 + lk) ^ (row & 7);
        av[m][ks] = *(const bf16x8*)&As[c][row * 64 + ch * 8];
      }
    #pragma unroll
    for (int n = 0; n < NF; ++n)
      #pragma unroll
      for (int ks = 0; ks < 2; ++ks) {
        const int row = wn * (BN / 4) + n * 16 + lrow;
        const int ch = (ks * 4 + lk) ^ (row & 7);
        bv[n][ks] = *(const bf16x8*)&Bs[c][row * 64 + ch * 8];
      }
    LGKM0();            // reads complete before anyone may overwrite buf[c]
    SB0();
    BAR();              // #1: all waves done reading buf[c]
    SB0();
    if (t + 2 < nt) stage(c, t + 2);   // overwrite freed buffer; loads fly under MFMA
    __builtin_amdgcn_s_setprio(1);
    #pragma unroll
    for (int ks = 0; ks < 2; ++ks)
      #pragma unroll
      for (int m = 0; m < 8; ++m)
        #pragma unroll
        for (int n = 0; n < NF; ++n)
          acc[m][n] = __builtin_amdgcn_mfma_f32_16x16x32_bf16(av[m][ks], bv[n][ks], acc[m][n], 0, 0, 0);
    __builtin_amdgcn_s_setprio(0);
    SB0();
    // counted wait: oldest LPT loads (tile t+1) landed; tile t+2 stays in flight
    if (t + 2 < nt) { if constexpr (LPT == 8) VMW(8); else VMW(6); }
    else if (t + 1 < nt) VMW(0);
    SB0();
    BAR();              // #2: buf[c^1] (tile t+1) ready for next iteration
    SB0();
  }

  // epilogue: C/D layout col=lane&15, row=(lane>>4)*4+j
  #pragma unroll
  for (int m = 0; m < 8; ++m) {
    const int row0 = by * 256 + wm * 128 + m * 16 + lk * 4;
    #pragma unroll
    for (int n = 0; n < NF; ++n) {
      const int col = bx * BN + wn * (BN / 4) + n * 16 + lrow;
      #pragma unroll
      for (int j = 0; j < 4; ++j) {
        const size_t idx = (size_t)(row0 + j) * N + col;
        if constexpr (OUT_BF16) ((ushort_t*)Cp)[idx] = f2bf(acc[m][n][j]);
        else                    ((float*)Cp)[idx] = acc[m][n][j];
      }
    }
  }
}

// ---------------- middle: h_all, router softmax, M = sum_p w (x) h ----------------
__global__ __launch_bounds__(256) void middle_kernel(const unsigned short* __restrict__ AH,
                                                     const float* __restrict__ fp,
                                                     const float* __restrict__ femb,
                                                     const float* __restrict__ Wr,
                                                     unsigned short* __restrict__ Mout,
                                                     float* __restrict__ auxout) {
  __shared__ float G[16][16];       // G[n][j] = sum_ds femb[n][ds]*Wr[ds][j]
  __shared__ float hs[4][2][128];
  __shared__ float wsm[4][2][16];
  const int tid = threadIdx.x;
  {
    const int n = tid >> 4, j = tid & 15;
    float s = 0.f;
    #pragma unroll
    for (int ds = 0; ds < 64; ++ds) s += femb[n * 64 + ds] * Wr[ds * 16 + j];
    G[n][j] = s;
  }
  const int wv = tid >> 6, l = tid & 63;
  const int t = blockIdx.x * 4 + wv;

  float p0[16], p1[16];
  #pragma unroll
  for (int n = 0; n < 16; ++n) {
    p0[n] = fp[t * 16 + n];
    p1[n] = fp[T_TOK * 16 + t * 16 + n];
  }

  float h00 = 0.f, h01 = 0.f, h10 = 0.f, h11 = 0.f;
  const unsigned short* ahrow = AH + (size_t)t * NRCOL;
  #pragma unroll
  for (int n = 0; n < 16; ++n) {
    const unsigned int v = *(const unsigned int*)(ahrow + n * 128 + 2 * l);
    const float a0 = bfbits2f(v & 0xffffu);
    const float a1 = bfbits2f(v >> 16);
    h00 += a0 * p0[n]; h01 += a1 * p0[n];
    h10 += a0 * p1[n]; h11 += a1 * p1[n];
  }
  hs[wv][0][2 * l] = h00; hs[wv][0][2 * l + 1] = h01;
  hs[wv][1][2 * l] = h10; hs[wv][1][2 * l + 1] = h11;
  __syncthreads();

  if (l < 32) {
    const int p = l >> 4, j = l & 15;
    float s = 0.f;
    #pragma unroll
    for (int n = 0; n < 16; ++n) s += (p ? p1[n] : p0[n]) * G[n][j];
    for (int r = 0; r < 128; ++r) s += hs[wv][p][r] * Wr[(64 + r) * 16 + j];
    float mx = s;
    #pragma unroll
    for (int d = 1; d < 16; d <<= 1) mx = fmaxf(mx, __shfl_xor(mx, d, 64));
    const float e = __expf(s - mx);
    float sum = e;
    #pragma unroll
    for (int d = 1; d < 16; d <<= 1) sum += __shfl_xor(sum, d, 64);
    wsm[wv][p][j] = e / sum;
  }
  __syncthreads();

  unsigned short* mrow = Mout + (size_t)t * NRCOL;
  #pragma unroll
  for (int n = 0; n < 16; ++n) {
    const float w0 = wsm[wv][0][n], w1 = wsm[wv][1][n];
    const float m0 = w0 * h00 + w1 * h10;   // r = 2l
    const float m1 = w0 * h01 + w1 * h11;   // r = 2l+1
    const unsigned int pk = (unsigned)f2bf(m0) | ((unsigned)f2bf(m1) << 16);
    *(unsigned int*)(mrow + n * 128 + 2 * l) = pk;
  }
  if (blockIdx.x == 0 && tid == 0) auxout[0] = 0.f;
}

extern "C" void kernel_launch(void* const* d_in, const int* in_sizes, int n_in,
                              void* d_out, int out_size, void* d_ws, size_t ws_size,
                              hipStream_t stream) {
  const float* x    = (const float*)d_in[0];
  const float* fp   = (const float*)d_in[1];
  const float* fk   = (const float*)d_in[2];
  const float* rk   = (const float*)d_in[3];
  const float* femb = (const float*)d_in[4];
  const float* Wr   = (const float*)d_in[5];
  float* out = (float*)d_out;

  char* ws = (char*)d_ws;
  unsigned short* Xbf = (unsigned short*)ws;
  unsigned short* W1t = (unsigned short*)(ws + 16u * 1024 * 1024);
  unsigned short* Mb  = (unsigned short*)ws;
  unsigned short* W2t = (unsigned short*)(ws + 32u * 1024 * 1024);
  unsigned short* AH  = (unsigned short*)(ws + 36u * 1024 * 1024);

  cvt_f32_bf16<<<2048, 256, 0, stream>>>(x, Xbf, (T_TOK * DIM) / 4);
  tcvt<<<dim3(128 / 32, 1024 / 32, 16), 256, 0, stream>>>(fk, W1t, 1024, 128,
                                                          1024L * 128, 128L * 1024);
  tcvt<<<dim3(1024 / 32, 2048 / 32, 1), 256, 0, stream>>>(rk, W2t, 2048, 1024, 0, 0);
  // all_h = Xbf @ W1t^T  -> AH bf16 [8192][2048]
  gemm8<256, true><<<dim3(NRCOL / 256, T_TOK / 256), 512, 0, stream>>>(Xbf, W1t, AH,
                                                                       NRCOL, DIM);
  middle_kernel<<<T_TOK / 4, 256, 0, stream>>>(AH, fp, femb, Wr, Mb, out + 8388608);
  // output = Mb @ W2t^T -> f32 d_out [8192][1024]
  gemm8<128, false><<<dim3(DIM / 128, T_TOK / 256), 512, 0, stream>>>(Mb, W2t, out,
                                                                      DIM, NRCOL);
}